// Round 11
// baseline (190.605 us; speedup 1.0000x reference)
//
#include <hip/hip_runtime.h>
#include <hip/hip_cooperative_groups.h>
#include <stdint.h>

namespace cg = cooperative_groups;

constexpr int DIN  = 256;
constexpr int DOUT = 32;

typedef float f32x4  __attribute__((ext_vector_type(4)));
typedef short bf16x8 __attribute__((ext_vector_type(8)));

__device__ __forceinline__ uint16_t f2bf(float f, float& back) {
    uint32_t u = __builtin_bit_cast(uint32_t, f);
    uint32_t r = (u + 0x7fffu + ((u >> 16) & 1u)) >> 16;   // RNE
    back = __builtin_bit_cast(float, r << 16);
    return (uint16_t)r;
}

// Cooperative fused kernel. Block = 64 entities (4 waves x 16). Phase 1:
// MFMA gemm (hi/lo bf16 split, B-frags converted inline from weight) with the
// block's contiguous zero-slice stores interleaved per k-tile (stores are
// independent of the compute chain; they drain at write BW underneath).
// proj stays in registers. threadfence + grid.sync makes all zeros visible
// device-wide (across XCDs). Phase 2: scatter own entities from registers
// into the now-zeroed, cache-hot planes.
__global__ __launch_bounds__(256, 2)
void k_coop(const float* __restrict__ emb, const float* __restrict__ weight,
            const float* __restrict__ bias, const int* __restrict__ ex,
            const int* __restrict__ ey, const int* __restrict__ en,
            const int* __restrict__ pW, float* __restrict__ out,
            int N, int nent, int HW, int zTotal4, int ZQ)
{
    const int tid  = threadIdx.x;
    const int lane = tid & 63;
    const int wv   = tid >> 6;
    const int eb   = blockIdx.x * 64 + wv * 16;
    const int row  = lane & 15;
    const int kg   = lane >> 4;

    int e = eb + row; if (e >= nent) e = nent - 1;
    const float* erow = emb + (size_t)e * DIN + kg * 8;

    float4* outv = (float4*)out;
    const float4 z4 = make_float4(0.f, 0.f, 0.f, 0.f);
    const size_t zslice = (size_t)blockIdx.x * ZQ * 256;
    int zq = 0;

    f32x4 acc0 = {0.f, 0.f, 0.f, 0.f};
    f32x4 acc1 = {0.f, 0.f, 0.f, 0.f};

    #pragma unroll
    for (int t = 0; t < 8; ++t) {
        // A-tile loads (16 rows x 128B per wave, coalesced-ish; R7-proven)
        const float4 a0 = *(const float4*)(erow + t * 32);
        const float4 a1 = *(const float4*)(erow + t * 32 + 4);
        // B loads straight from weight (32 KB, L1/L2-resident; k = t*32+kg*8+j)
        const float* wp = weight + (size_t)(t * 32 + kg * 8) * DOUT + row;
        float wf0[8], wf1[8];
        #pragma unroll
        for (int j = 0; j < 8; ++j) {
            wf0[j] = wp[(size_t)j * DOUT];
            wf1[j] = wp[(size_t)j * DOUT + 16];
        }
        // interleaved zero stores: 12 contiguous-1KB bursts per k-tile
        #pragma unroll
        for (int q = 0; q < 12; ++q) {
            if (zq < ZQ) {
                const size_t idx = zslice + (size_t)zq * 256 + tid;
                if (idx < (size_t)zTotal4) outv[idx] = z4;
            }
            ++zq;
        }
        // convert to hi/lo bf16
        const float af[8] = {a0.x, a0.y, a0.z, a0.w, a1.x, a1.y, a1.z, a1.w};
        bf16x8 ahi, alo, bh0, bl0, bh1, bl1;
        #pragma unroll
        for (int j = 0; j < 8; ++j) {
            float back, b2;
            const uint16_t h = f2bf(af[j], back);
            const uint16_t l = f2bf(af[j] - back, b2);
            ahi[j] = (short)h; alo[j] = (short)l;
        }
        #pragma unroll
        for (int j = 0; j < 8; ++j) {
            float back, b2;
            const uint16_t h = f2bf(wf0[j], back);
            const uint16_t l = f2bf(wf0[j] - back, b2);
            bh0[j] = (short)h; bl0[j] = (short)l;
        }
        #pragma unroll
        for (int j = 0; j < 8; ++j) {
            float back, b2;
            const uint16_t h = f2bf(wf1[j], back);
            const uint16_t l = f2bf(wf1[j] - back, b2);
            bh1[j] = (short)h; bl1[j] = (short)l;
        }
        acc0 = __builtin_amdgcn_mfma_f32_16x16x32_bf16(ahi, bh0, acc0, 0, 0, 0);
        acc1 = __builtin_amdgcn_mfma_f32_16x16x32_bf16(ahi, bh1, acc1, 0, 0, 0);
        acc0 = __builtin_amdgcn_mfma_f32_16x16x32_bf16(alo, bh0, acc0, 0, 0, 0);
        acc1 = __builtin_amdgcn_mfma_f32_16x16x32_bf16(alo, bh1, acc1, 0, 0, 0);
        acc0 = __builtin_amdgcn_mfma_f32_16x16x32_bf16(ahi, bl0, acc0, 0, 0, 0);
        acc1 = __builtin_amdgcn_mfma_f32_16x16x32_bf16(ahi, bl1, acc1, 0, 0, 0);
    }
    // tail zero stores
    while (zq < ZQ) {
        const size_t idx = zslice + (size_t)zq * 256 + tid;
        if (idx < (size_t)zTotal4) outv[idx] = z4;
        ++zq;
    }

    __threadfence();            // device-scope: zeros visible across XCDs
    cg::this_grid().sync();

    // ---- phase 2: scatter own entities from registers
    // C/D layout: col = lane&15, row = (lane>>4)*4 + reg (m89/m91; R7/R9-proven)
    const float b0 = bias[row], b1 = bias[row + 16];
    const int Wd = *pW;
    #pragma unroll
    for (int r = 0; r < 4; ++r) {
        const int ent = eb + kg * 4 + r;
        if (ent >= nent) continue;
        const int bb = ent / N, nn = ent - bb * N;
        if (nn >= en[bb]) continue;
        const int hw = ey[ent] * Wd + ex[ent];
        const float v0 = fmaxf(acc0[r] + b0, 0.f);
        const float v1 = fmaxf(acc1[r] + b1, 0.f);
        if (v0 != 0.f) atomicAdd(out + (size_t)(bb * DOUT + row) * HW + hw, v0);
        if (v1 != 0.f) atomicAdd(out + (size_t)(bb * DOUT + row + 16) * HW + hw, v1);
    }
}

// ---------------- fallback: memset + R4's proven fused kernel ----------------
constexpr int FET = 64, FKT = 64, FEP = FKT + 4;
__global__ __launch_bounds__(256)
void enc_fallback(const float* __restrict__ emb, const float* __restrict__ weight,
                  const float* __restrict__ bias, const int* __restrict__ ex,
                  const int* __restrict__ ey, const int* __restrict__ en,
                  const int* __restrict__ pW, float* __restrict__ out,
                  int N, int nent, int HW)
{
    __shared__ float s_emb[FET][FEP];
    __shared__ float s_w[FKT * DOUT];
    const int tid = threadIdx.x;
    const int og = tid & 7, eg = tid >> 3;
    const int eb = blockIdx.x * FET;
    float4 pe[4]; float4 pw[2];
    #pragma unroll
    for (int r = 0; r < 4; ++r) {
        int f = (r << 8) + tid, rw = f >> 4, col = (f & 15) << 2;
        int e = eb + rw; if (e >= nent) e = nent - 1;
        pe[r] = *(const float4*)&emb[(size_t)e * DIN + col];
    }
    #pragma unroll
    for (int r = 0; r < 2; ++r) pw[r] = *(const float4*)&weight[(size_t)(((r << 8) + tid) << 2)];
    float acc[2][4] = {{0,0,0,0},{0,0,0,0}};
    for (int t = 0; t < 4; ++t) {
        #pragma unroll
        for (int r = 0; r < 4; ++r) {
            int f = (r << 8) + tid;
            *(float4*)&s_emb[f >> 4][(f & 15) << 2] = pe[r];
        }
        #pragma unroll
        for (int r = 0; r < 2; ++r) *(float4*)&s_w[((r << 8) + tid) << 2] = pw[r];
        __syncthreads();
        if (t < 3) {
            const int kt = (t + 1) * FKT;
            #pragma unroll
            for (int r = 0; r < 4; ++r) {
                int f = (r << 8) + tid, rw = f >> 4, col = (f & 15) << 2;
                int e = eb + rw; if (e >= nent) e = nent - 1;
                pe[r] = *(const float4*)&emb[(size_t)e * DIN + kt + col];
            }
            #pragma unroll
            for (int r = 0; r < 2; ++r)
                pw[r] = *(const float4*)&weight[(size_t)kt * DOUT + (((r << 8) + tid) << 2)];
        }
        #pragma unroll
        for (int k = 0; k < FKT; k += 4) {
            float4 e0 = *(const float4*)&s_emb[eg][k];
            float4 e1 = *(const float4*)&s_emb[eg + 32][k];
            float4 w0 = *(const float4*)&s_w[(k + 0) * DOUT + og * 4];
            float4 w1 = *(const float4*)&s_w[(k + 1) * DOUT + og * 4];
            float4 w2 = *(const float4*)&s_w[(k + 2) * DOUT + og * 4];
            float4 w3 = *(const float4*)&s_w[(k + 3) * DOUT + og * 4];
            acc[0][0] += e0.x*w0.x + e0.y*w1.x + e0.z*w2.x + e0.w*w3.x;
            acc[0][1] += e0.x*w0.y + e0.y*w1.y + e0.z*w2.y + e0.w*w3.y;
            acc[0][2] += e0.x*w0.z + e0.y*w1.z + e0.z*w2.z + e0.w*w3.z;
            acc[0][3] += e0.x*w0.w + e0.y*w1.w + e0.z*w2.w + e0.w*w3.w;
            acc[1][0] += e1.x*w0.x + e1.y*w1.x + e1.z*w2.x + e1.w*w3.x;
            acc[1][1] += e1.x*w0.y + e1.y*w1.y + e1.z*w2.y + e1.w*w3.y;
            acc[1][2] += e1.x*w0.z + e1.y*w1.z + e1.z*w2.z + e1.w*w3.z;
            acc[1][3] += e1.x*w0.w + e1.y*w1.w + e1.z*w2.w + e1.w*w3.w;
        }
        __syncthreads();
    }
    const int W = *pW;
    const float4 bv = *(const float4*)&bias[og * 4];
    #pragma unroll
    for (int i = 0; i < 2; ++i) {
        int ent = eb + eg + i * 32;
        if (ent >= nent) continue;
        int b = ent / N, n = ent - b * N;
        if (n >= en[b]) continue;
        float* dst = out + ((size_t)b * DOUT + og * 4) * (size_t)HW
                         + (size_t)ey[ent] * W + ex[ent];
        float v0 = fmaxf(acc[i][0] + bv.x, 0.f);
        float v1 = fmaxf(acc[i][1] + bv.y, 0.f);
        float v2 = fmaxf(acc[i][2] + bv.z, 0.f);
        float v3 = fmaxf(acc[i][3] + bv.w, 0.f);
        if (v0 != 0.f) atomicAdd(dst + 0 * (size_t)HW, v0);
        if (v1 != 0.f) atomicAdd(dst + 1 * (size_t)HW, v1);
        if (v2 != 0.f) atomicAdd(dst + 2 * (size_t)HW, v2);
        if (v3 != 0.f) atomicAdd(dst + 3 * (size_t)HW, v3);
    }
}

extern "C" void kernel_launch(void* const* d_in, const int* in_sizes, int n_in,
                              void* d_out, int out_size, void* d_ws, size_t ws_size,
                              hipStream_t stream) {
    const float* emb    = (const float*)d_in[0];
    const float* weight = (const float*)d_in[1];
    const float* bias   = (const float*)d_in[2];
    const int*   ex     = (const int*)d_in[3];
    const int*   ey     = (const int*)d_in[4];
    const int*   en     = (const int*)d_in[5];
    const int*   pW     = (const int*)d_in[7];
    float*       out    = (float*)d_out;

    int nent = in_sizes[3];                          // B*N
    const int B    = in_sizes[5];
    const int N    = nent / B;
    const int DIN_rt = in_sizes[0] / nent;
    const int HW   = (int)((size_t)out_size / ((size_t)B * DOUT));
    const int zTotal4 = out_size / 4;

    const int grid = (nent + 63) / 64;
    const int ZQ = (zTotal4 + grid * 256 - 1) / (grid * 256);

    const bool coop_ok = (DIN_rt == DIN) && (in_sizes[2] == DOUT) &&
                         (out_size % 4 == 0) && (B * N == nent) &&
                         (grid <= 512);              // co-residency: <=2 blocks/CU

    bool done = false;
    if (coop_ok) {
        void* args[] = { (void*)&emb, (void*)&weight, (void*)&bias, (void*)&ex,
                         (void*)&ey, (void*)&en, (void*)&pW, (void*)&out,
                         (void*)&N, (void*)&nent, (void*)&HW,
                         (void*)&zTotal4, (void*)&ZQ };
        hipError_t err = hipLaunchCooperativeKernel((const void*)k_coop,
                                                    dim3(grid), dim3(256),
                                                    args, 0, stream);
        done = (err == hipSuccess);
    }
    if (!done) {
        (void)hipMemsetAsync(d_out, 0, (size_t)out_size * sizeof(float), stream);
        const int blocks = (nent + FET - 1) / FET;
        enc_fallback<<<blocks, 256, 0, stream>>>(emb, weight, bias, ex, ey, en, pW,
                                                 out, N, nent, HW);
    }
}

// Round 12
// 46.424 us; speedup vs baseline: 4.1057x; 4.1057x over previous
//
#include <hip/hip_runtime.h>
#include <stdint.h>

constexpr int DIN  = 256;
constexpr int DOUT = 32;
constexpr int ZSPLIT = 2;    // half-planes -> B*DOUT*2 = 4096 zero/scatter blocks

typedef float f32x4  __attribute__((ext_vector_type(4)));
typedef short bf16x8 __attribute__((ext_vector_type(8)));

__device__ __forceinline__ uint16_t f2bf(float f, float& back) {
    uint32_t u = __builtin_bit_cast(uint32_t, f);
    uint32_t r = (u + 0x7fffu + ((u >> 16) & 1u)) >> 16;   // RNE
    back = __builtin_bit_cast(float, r << 16);
    return (uint16_t)r;
}

// gemm: MFMA hi/lo-split bf16, W fragments converted inline (no prep kernel;
// numerics proven in R11, absmax 0.0156). wave = 16 entities x 32 outs.
// Epilogue -> proj[nent][32] in ws.
__global__ __launch_bounds__(256)
void k_gemm(const float* __restrict__ emb,
            const float* __restrict__ weight,
            const float* __restrict__ bias,
            float* __restrict__ proj,
            int nent)
{
    const int tid  = threadIdx.x;
    const int lane = tid & 63;
    const int wv   = tid >> 6;
    const int eb   = blockIdx.x * 64 + wv * 16;
    const int row  = lane & 15;
    const int kg   = lane >> 4;

    int e = eb + row; if (e >= nent) e = nent - 1;
    const float* erow = emb + (size_t)e * DIN + kg * 8;

    f32x4 acc0 = {0.f, 0.f, 0.f, 0.f};
    f32x4 acc1 = {0.f, 0.f, 0.f, 0.f};

    #pragma unroll
    for (int t = 0; t < 8; ++t) {
        // A: lane reads emb[row][k = t*32 + kg*8 + j]  (fp32, 2x float4)
        const float4 a0 = *(const float4*)(erow + t * 32);
        const float4 a1 = *(const float4*)(erow + t * 32 + 4);
        // B: lane reads weight[k][col] for col = row (+16) straight from global
        const float* wp = weight + (size_t)(t * 32 + kg * 8) * DOUT + row;
        float wf0[8], wf1[8];
        #pragma unroll
        for (int j = 0; j < 8; ++j) {
            wf0[j] = wp[(size_t)j * DOUT];
            wf1[j] = wp[(size_t)j * DOUT + 16];
        }
        const float af[8] = {a0.x, a0.y, a0.z, a0.w, a1.x, a1.y, a1.z, a1.w};
        bf16x8 ahi, alo, bh0, bl0, bh1, bl1;
        #pragma unroll
        for (int j = 0; j < 8; ++j) {
            float back, b2;
            const uint16_t h = f2bf(af[j], back);
            const uint16_t l = f2bf(af[j] - back, b2);
            ahi[j] = (short)h; alo[j] = (short)l;
        }
        #pragma unroll
        for (int j = 0; j < 8; ++j) {
            float back, b2;
            const uint16_t h = f2bf(wf0[j], back);
            const uint16_t l = f2bf(wf0[j] - back, b2);
            bh0[j] = (short)h; bl0[j] = (short)l;
        }
        #pragma unroll
        for (int j = 0; j < 8; ++j) {
            float back, b2;
            const uint16_t h = f2bf(wf1[j], back);
            const uint16_t l = f2bf(wf1[j] - back, b2);
            bh1[j] = (short)h; bl1[j] = (short)l;
        }
        acc0 = __builtin_amdgcn_mfma_f32_16x16x32_bf16(ahi, bh0, acc0, 0, 0, 0);
        acc1 = __builtin_amdgcn_mfma_f32_16x16x32_bf16(ahi, bh1, acc1, 0, 0, 0);
        acc0 = __builtin_amdgcn_mfma_f32_16x16x32_bf16(alo, bh0, acc0, 0, 0, 0);
        acc1 = __builtin_amdgcn_mfma_f32_16x16x32_bf16(alo, bh1, acc1, 0, 0, 0);
        acc0 = __builtin_amdgcn_mfma_f32_16x16x32_bf16(ahi, bl0, acc0, 0, 0, 0);
        acc1 = __builtin_amdgcn_mfma_f32_16x16x32_bf16(ahi, bl1, acc1, 0, 0, 0);
    }

    // C/D layout: col = lane&15, row = (lane>>4)*4 + reg (m89/m91; R7/R9-proven)
    const int c0 = lane & 15, c1 = c0 + 16;
    const float b0 = bias[c0], b1 = bias[c1];
    #pragma unroll
    for (int r = 0; r < 4; ++r) {
        const int ent = eb + (lane >> 4) * 4 + r;
        if (ent >= nent) continue;
        proj[(size_t)ent * DOUT + c0] = fmaxf(acc0[r] + b0, 0.f);
        proj[(size_t)ent * DOUT + c1] = fmaxf(acc1[r] + b1, 0.f);
    }
}

// zs: block = (b, c, half). Zero its contiguous half-plane (50 KB) with
// temporal float4 stores, barrier, then scatter batch b's in-range entities
// for channel c into the L2-hot half-plane. 4096 blocks -> 16/CU of
// store-issuing waves (write-BW needs wave parallelism; R11 lesson).
__global__ __launch_bounds__(256)
void k_zs(const float* __restrict__ proj,
          const int* __restrict__ ex, const int* __restrict__ ey,
          const int* __restrict__ en, const int* __restrict__ pW,
          float* __restrict__ out,
          int N, int nent, int HW)
{
    const int tid = threadIdx.x;
    const int idx = blockIdx.x;
    const int h   = idx & (ZSPLIT - 1);
    const int c   = (idx >> 1) & 31;
    const int b   = idx >> 6;

    float* plane = out + ((size_t)b * DOUT + c) * (size_t)HW;
    const int seglen = HW / ZSPLIT;
    const int s0 = h * seglen;

    // ---- zero the half-plane (contiguous stream)
    float4* p = (float4*)(plane + s0);
    const int n4 = seglen >> 2;
    for (int i = tid; i < n4; i += 256)
        p[i] = make_float4(0.f, 0.f, 0.f, 0.f);
    __syncthreads();

    // ---- scatter in-range entities, this channel
    const int cnt = min(en[b], N);
    const int W = *pW;
    const int base = b * N;
    const int send = s0 + seglen;
    for (int slot = tid; slot < cnt; slot += 256) {
        const int ent = base + slot;
        if (ent >= nent) break;
        const int hw = ey[ent] * W + ex[ent];
        if (hw < s0 || hw >= send) continue;
        const float v = proj[(size_t)ent * DOUT + c];
        if (v != 0.f) atomicAdd(plane + hw, v);
    }
}

// ---------------- fallback: memset + R4's proven fused kernel ----------------
constexpr int FET = 64, FKT = 64, FEP = FKT + 4;
__global__ __launch_bounds__(256)
void enc_fallback(const float* __restrict__ emb, const float* __restrict__ weight,
                  const float* __restrict__ bias, const int* __restrict__ ex,
                  const int* __restrict__ ey, const int* __restrict__ en,
                  const int* __restrict__ pW, float* __restrict__ out,
                  int N, int nent, int HW)
{
    __shared__ float s_emb[FET][FEP];
    __shared__ float s_w[FKT * DOUT];
    const int tid = threadIdx.x;
    const int og = tid & 7, eg = tid >> 3;
    const int eb = blockIdx.x * FET;
    float4 pe[4]; float4 pw[2];
    #pragma unroll
    for (int r = 0; r < 4; ++r) {
        int f = (r << 8) + tid, rw = f >> 4, col = (f & 15) << 2;
        int e = eb + rw; if (e >= nent) e = nent - 1;
        pe[r] = *(const float4*)&emb[(size_t)e * DIN + col];
    }
    #pragma unroll
    for (int r = 0; r < 2; ++r) pw[r] = *(const float4*)&weight[(size_t)(((r << 8) + tid) << 2)];
    float acc[2][4] = {{0,0,0,0},{0,0,0,0}};
    for (int t = 0; t < 4; ++t) {
        #pragma unroll
        for (int r = 0; r < 4; ++r) {
            int f = (r << 8) + tid;
            *(float4*)&s_emb[f >> 4][(f & 15) << 2] = pe[r];
        }
        #pragma unroll
        for (int r = 0; r < 2; ++r) *(float4*)&s_w[((r << 8) + tid) << 2] = pw[r];
        __syncthreads();
        if (t < 3) {
            const int kt = (t + 1) * FKT;
            #pragma unroll
            for (int r = 0; r < 4; ++r) {
                int f = (r << 8) + tid, rw = f >> 4, col = (f & 15) << 2;
                int e = eb + rw; if (e >= nent) e = nent - 1;
                pe[r] = *(const float4*)&emb[(size_t)e * DIN + kt + col];
            }
            #pragma unroll
            for (int r = 0; r < 2; ++r)
                pw[r] = *(const float4*)&weight[(size_t)kt * DOUT + (((r << 8) + tid) << 2)];
        }
        #pragma unroll
        for (int k = 0; k < FKT; k += 4) {
            float4 e0 = *(const float4*)&s_emb[eg][k];
            float4 e1 = *(const float4*)&s_emb[eg + 32][k];
            float4 w0 = *(const float4*)&s_w[(k + 0) * DOUT + og * 4];
            float4 w1 = *(const float4*)&s_w[(k + 1) * DOUT + og * 4];
            float4 w2 = *(const float4*)&s_w[(k + 2) * DOUT + og * 4];
            float4 w3 = *(const float4*)&s_w[(k + 3) * DOUT + og * 4];
            acc[0][0] += e0.x*w0.x + e0.y*w1.x + e0.z*w2.x + e0.w*w3.x;
            acc[0][1] += e0.x*w0.y + e0.y*w1.y + e0.z*w2.y + e0.w*w3.y;
            acc[0][2] += e0.x*w0.z + e0.y*w1.z + e0.z*w2.z + e0.w*w3.z;
            acc[0][3] += e0.x*w0.w + e0.y*w1.w + e0.z*w2.w + e0.w*w3.w;
            acc[1][0] += e1.x*w0.x + e1.y*w1.x + e1.z*w2.x + e1.w*w3.x;
            acc[1][1] += e1.x*w0.y + e1.y*w1.y + e1.z*w2.y + e1.w*w3.y;
            acc[1][2] += e1.x*w0.z + e1.y*w1.z + e1.z*w2.z + e1.w*w3.z;
            acc[1][3] += e1.x*w0.w + e1.y*w1.w + e1.z*w2.w + e1.w*w3.w;
        }
        __syncthreads();
    }
    const int W = *pW;
    const float4 bv = *(const float4*)&bias[og * 4];
    #pragma unroll
    for (int i = 0; i < 2; ++i) {
        int ent = eb + eg + i * 32;
        if (ent >= nent) continue;
        int b = ent / N, n = ent - b * N;
        if (n >= en[b]) continue;
        float* dst = out + ((size_t)b * DOUT + og * 4) * (size_t)HW
                         + (size_t)ey[ent] * W + ex[ent];
        float v0 = fmaxf(acc[i][0] + bv.x, 0.f);
        float v1 = fmaxf(acc[i][1] + bv.y, 0.f);
        float v2 = fmaxf(acc[i][2] + bv.z, 0.f);
        float v3 = fmaxf(acc[i][3] + bv.w, 0.f);
        if (v0 != 0.f) atomicAdd(dst + 0 * (size_t)HW, v0);
        if (v1 != 0.f) atomicAdd(dst + 1 * (size_t)HW, v1);
        if (v2 != 0.f) atomicAdd(dst + 2 * (size_t)HW, v2);
        if (v3 != 0.f) atomicAdd(dst + 3 * (size_t)HW, v3);
    }
}

extern "C" void kernel_launch(void* const* d_in, const int* in_sizes, int n_in,
                              void* d_out, int out_size, void* d_ws, size_t ws_size,
                              hipStream_t stream) {
    const float* emb    = (const float*)d_in[0];
    const float* weight = (const float*)d_in[1];
    const float* bias   = (const float*)d_in[2];
    const int*   ex     = (const int*)d_in[3];
    const int*   ey     = (const int*)d_in[4];
    const int*   en     = (const int*)d_in[5];
    const int*   pW     = (const int*)d_in[7];
    float*       out    = (float*)d_out;

    const int nent = in_sizes[3];                    // B*N
    const int B    = in_sizes[5];
    const int N    = nent / B;
    const int DIN_rt = in_sizes[0] / nent;
    const int HW   = (int)((size_t)out_size / ((size_t)B * DOUT));

    float* proj = (float*)d_ws;
    const size_t ws_need = (size_t)nent * DOUT * sizeof(float);

    const bool fused_ok = (ws_size >= ws_need) && (DIN_rt == DIN) &&
                          (in_sizes[2] == DOUT) && (B * N == nent) &&
                          (HW % (4 * ZSPLIT) == 0);

    if (fused_ok) {
        k_gemm<<<(nent + 63) / 64, 256, 0, stream>>>(emb, weight, bias, proj, nent);
        k_zs<<<B * DOUT * ZSPLIT, 256, 0, stream>>>(proj, ex, ey, en, pW, out,
                                                    N, nent, HW);
    } else {
        (void)hipMemsetAsync(d_out, 0, (size_t)out_size * sizeof(float), stream);
        const int blocks = (nent + FET - 1) / FET;
        enc_fallback<<<blocks, 256, 0, stream>>>(emb, weight, bias, ex, ey, en, pW,
                                                 out, N, nent, HW);
    }
}